// Round 8
// baseline (1834.419 us; speedup 1.0000x reference)
//
#include <hip/hip_runtime.h>
#include <math.h>

#define DD 16
#define HH 64
#define WW 64
#define VV (DD*HH*WW)      // 65536
#define CC 64
#define NHEADS 4
#define NSAMP 8
#define HDIM 16

typedef unsigned int uint;
typedef unsigned short ushort;
typedef __attribute__((ext_vector_type(8))) short bf16x8;
typedef __attribute__((ext_vector_type(4))) float f32x4;
typedef __attribute__((ext_vector_type(2))) float f32x2;

#if __has_builtin(__builtin_amdgcn_cvt_pk_f32_fp8) && __has_builtin(__builtin_amdgcn_cvt_pk_fp8_f32)
#define USE_FP8 1
#else
#define USE_FP8 0
#endif

#if USE_FP8
#define VOLU 8      // uints per (head,voxel): 32 fp8 ch = 32 B
#else
#define VOLU 16     // 32 bf16 ch = 64 B
#endif

__device__ __forceinline__ float clampf(float v, float lo, float hi){ return fminf(fmaxf(v, lo), hi); }
__device__ __forceinline__ int imin(int a, int b){ return a < b ? a : b; }
__device__ __forceinline__ int imax(int a, int b){ return a > b ? a : b; }

// bf16 helpers (RNE)
__device__ __forceinline__ ushort f2bf(float f){
  uint u = __float_as_uint(f);
  uint r = (u + 0x7fffu + ((u>>16)&1u)) >> 16;
  return (ushort)r;
}
__device__ __forceinline__ uint packbf2(float a, float b){
  return (uint)f2bf(a) | ((uint)f2bf(b) << 16);
}
__device__ __forceinline__ float bflo(uint u){ return __uint_as_float(u << 16); }
__device__ __forceinline__ float bfhi(uint u){ return __uint_as_float(u & 0xffff0000u); }
__device__ __forceinline__ float bf2f(ushort u){ return __uint_as_float((uint)u << 16); }

__device__ __forceinline__ float dot8(uint4 k, const float* q){
  return q[0]*bflo(k.x)+q[1]*bfhi(k.x)+q[2]*bflo(k.y)+q[3]*bfhi(k.y)
       + q[4]*bflo(k.z)+q[5]*bfhi(k.z)+q[6]*bflo(k.w)+q[7]*bfhi(k.w);
}
__device__ __forceinline__ void acc8(uint4 u, float cw, float* val){
  val[0]+=cw*bflo(u.x); val[1]+=cw*bfhi(u.x);
  val[2]+=cw*bflo(u.y); val[3]+=cw*bfhi(u.y);
  val[4]+=cw*bflo(u.z); val[5]+=cw*bfhi(u.z);
  val[6]+=cw*bflo(u.w); val[7]+=cw*bfhi(u.w);
}

#if USE_FP8
__device__ __forceinline__ float dot16_fp8(uint4 u, const float* q){
  f32x2 p; float s = 0.f;
  p = __builtin_amdgcn_cvt_pk_f32_fp8(u.x,false); s += q[0]*p[0]  + q[1]*p[1];
  p = __builtin_amdgcn_cvt_pk_f32_fp8(u.x,true ); s += q[2]*p[0]  + q[3]*p[1];
  p = __builtin_amdgcn_cvt_pk_f32_fp8(u.y,false); s += q[4]*p[0]  + q[5]*p[1];
  p = __builtin_amdgcn_cvt_pk_f32_fp8(u.y,true ); s += q[6]*p[0]  + q[7]*p[1];
  p = __builtin_amdgcn_cvt_pk_f32_fp8(u.z,false); s += q[8]*p[0]  + q[9]*p[1];
  p = __builtin_amdgcn_cvt_pk_f32_fp8(u.z,true ); s += q[10]*p[0] + q[11]*p[1];
  p = __builtin_amdgcn_cvt_pk_f32_fp8(u.w,false); s += q[12]*p[0] + q[13]*p[1];
  p = __builtin_amdgcn_cvt_pk_f32_fp8(u.w,true ); s += q[14]*p[0] + q[15]*p[1];
  return s;
}
__device__ __forceinline__ void acc16_fp8(uint4 u, float cw, float* val){
  f32x2 p;
  p = __builtin_amdgcn_cvt_pk_f32_fp8(u.x,false); val[0] += cw*p[0];  val[1] += cw*p[1];
  p = __builtin_amdgcn_cvt_pk_f32_fp8(u.x,true ); val[2] += cw*p[0];  val[3] += cw*p[1];
  p = __builtin_amdgcn_cvt_pk_f32_fp8(u.y,false); val[4] += cw*p[0];  val[5] += cw*p[1];
  p = __builtin_amdgcn_cvt_pk_f32_fp8(u.y,true ); val[6] += cw*p[0];  val[7] += cw*p[1];
  p = __builtin_amdgcn_cvt_pk_f32_fp8(u.z,false); val[8] += cw*p[0];  val[9] += cw*p[1];
  p = __builtin_amdgcn_cvt_pk_f32_fp8(u.z,true ); val[10]+= cw*p[0];  val[11]+= cw*p[1];
  p = __builtin_amdgcn_cvt_pk_f32_fp8(u.w,false); val[12]+= cw*p[0];  val[13]+= cw*p[1];
  p = __builtin_amdgcn_cvt_pk_f32_fp8(u.w,true ); val[14]+= cw*p[0];  val[15]+= cw*p[1];
}
#endif

// ---- weight repacks ------------------------------------------------------
// 3x3x3 conv weights -> bf16 pairs in exact MFMA A-fragment order.
__global__ void repack_wmfma(const float* __restrict__ w, uint* __restrict__ o, int MG){
  int U = blockIdx.x*256 + threadIdx.x;
  int total = 54*MG*256;
  if (U >= total) return;
  int j2 = U & 3;
  int m  = (U>>2) & 15;
  int q  = (U>>6) & 3;
  int rest = U >> 8;          // s*MG + g
  int g = rest % MG;
  int s = rest / MG;
  int tap = s >> 1, h = s & 1;
  int co = g*16 + m;
  int ci = h*32 + q*8 + j2*2;
  int base = co*1728 + ci*27 + tap;
  o[U] = packbf2(w[base], w[base + 27]);
}
// 1x1 conv weights [co][64ci] -> bf16 A-fragments: frag = ks*MT+mt
__global__ void repack_w1mfma(const float* __restrict__ w, uint* __restrict__ o, int MT){
  int U = blockIdx.x*256 + threadIdx.x;
  int total = 2*MT*256;
  if (U >= total) return;
  int j2 = U & 3;
  int lane = (U>>2) & 63;
  int frag = U >> 8;
  int mt = frag % MT;
  int ks = frag / MT;
  int q = lane >> 4, m = lane & 15;
  int co = mt*16 + m;
  int ci = ks*32 + q*8 + j2*2;
  o[U] = packbf2(w[co*CC + ci], w[co*CC + ci + 1]);
}

// ---- 1x1 conv via MFMA ---------------------------------------------------
// EPI 0: +bias -> vols[head][y][x][z][32ch] fp8 (or bf16 fallback), grid 1024
// EPI 1: (acc+bias)*0.25 -> bf16 out[call][co][v]  (q, CO=64, grid 2048)
template<int CO, int EPI>
__global__ __launch_bounds__(256) void conv1_mfma(
    const float* __restrict__ xa, const float* __restrict__ xb,
    const uint* __restrict__ wA, const float* __restrict__ bias,
    void* __restrict__ outp)
{
  constexpr int MT = CO/16;
  constexpr int MW = MT/4;
  __shared__ ushort xt[64*72];    // 9216 B
  int tid = threadIdx.x;
  int lane = tid & 63;
  int g = __builtin_amdgcn_readfirstlane(tid >> 6);
  int q = lane >> 4, n = lane & 15;
  int call = blockIdx.x >> 10;
  int v0 = (blockIdx.x & 1023) * 64;
  const float* x = call ? xb : xa;
  for (int it = tid; it < 64*32; it += 256){
    int vox = it & 63; int cp = it >> 6;    // ci pair
    float a = x[(size_t)(2*cp)*VV + v0 + vox];
    float b = x[(size_t)(2*cp+1)*VV + v0 + vox];
    *reinterpret_cast<uint*>(&xt[vox*72 + 2*cp]) = packbf2(a,b);
  }
  __syncthreads();
  f32x4 acc[MW][4];
  #pragma unroll
  for (int mw=0;mw<MW;mw++)
    #pragma unroll
    for (int nt=0;nt<4;nt++){ acc[mw][nt].x=0.f; acc[mw][nt].y=0.f; acc[mw][nt].z=0.f; acc[mw][nt].w=0.f; }
  const char* ldsb = reinterpret_cast<const char*>(xt);
  const char* wac  = reinterpret_cast<const char*>(wA);
  #pragma unroll
  for (int ks=0; ks<2; ks++){
    bf16x8 bfr[4];
    #pragma unroll
    for (int nt=0; nt<4; nt++)
      bfr[nt] = *reinterpret_cast<const bf16x8*>(ldsb + ((nt*16+n)*144 + q*16 + ks*64));
    #pragma unroll
    for (int mw=0; mw<MW; mw++){
      int mt = g*MW + mw;
      bf16x8 af = *reinterpret_cast<const bf16x8*>(wac + (size_t)((ks*MT + mt)*64 + lane)*16);
      #pragma unroll
      for (int nt=0; nt<4; nt++)
        acc[mw][nt] = __builtin_amdgcn_mfma_f32_16x16x32_bf16(af, bfr[nt], acc[mw][nt], 0, 0, 0);
    }
  }
  #pragma unroll
  for (int mw=0; mw<MW; mw++){
    int mt = g*MW + mw;
    int cob = mt*16 + q*4;
    #pragma unroll
    for (int nt=0; nt<4; nt++){
      int v = v0 + nt*16 + n;
      float r0 = acc[mw][nt].x + bias[cob+0];
      float r1 = acc[mw][nt].y + bias[cob+1];
      float r2 = acc[mw][nt].z + bias[cob+2];
      float r3 = acc[mw][nt].w + bias[cob+3];
      if (EPI == 0){
        int z = v >> 12, y = (v >> 6) & 63, xx = v & 63;
        int head = cob >> 5;
        uint* vols = (uint*)outp;
        size_t rec = (size_t)head*VV + (size_t)(y*WW+xx)*DD + z;
#if USE_FP8
        uint u0 = (uint)__builtin_amdgcn_cvt_pk_fp8_f32(r0, r1, 0, false);
        u0 = (uint)__builtin_amdgcn_cvt_pk_fp8_f32(r2, r3, (int)u0, true);
        vols[rec*VOLU + ((cob&31)>>2)] = u0;
#else
        uint2 pk; pk.x = packbf2(r0,r1); pk.y = packbf2(r2,r3);
        *reinterpret_cast<uint2*>(vols + rec*VOLU + ((cob&31)>>1)) = pk;
#endif
      } else {
        ushort* ob = (ushort*)outp + (size_t)call*CC*VV;
        ob[(size_t)(cob+0)*VV + v] = f2bf(r0*0.25f);
        ob[(size_t)(cob+1)*VV + v] = f2bf(r1*0.25f);
        ob[(size_t)(cob+2)*VV + v] = f2bf(r2*0.25f);
        ob[(size_t)(cob+3)*VV + v] = f2bf(r3*0.25f);
      }
    }
  }
}

// ---- 3x3x3 conv via implicit-GEMM MFMA, batched over 2 calls -------------
template<int CO, int INPK, int OUTPK>
__global__ __launch_bounds__(256) void conv3_mfma(
    const float* __restrict__ xa, const float* __restrict__ xb,
    const uint* __restrict__ xpk,
    const uint* __restrict__ wA, const float* __restrict__ bias,
    void* __restrict__ outp)
{
  constexpr int MG = CO/16;
  constexpr int MROW = CO/32;
  __shared__ ushort xh[300*40];   // 24 KB
  int tid = threadIdx.x;
  int lane = tid & 63;
  int w = __builtin_amdgcn_readfirstlane(tid >> 6);
  int q = lane >> 4, n = lane & 15;
  int bid = blockIdx.x;           // 0..2047
  int xcd = bid & 7, islot = bid >> 3;
  int call = islot >> 7;
  int z = xcd*2 + ((islot >> 6) & 1);
  int rem = islot & 63;
  int by = (rem >> 3) << 3, bx = (rem & 7) << 3;

  const float* xin = call ? xb : xa;
  const uint* xinp = xpk + (size_t)call*32*VV;

  int mbase = (w & 1) * MROW;
  int np = w >> 1;
  int lo[2];
  #pragma unroll
  for (int nt=0;nt<2;nt++){
    int vox = (np*2+nt)*16 + n;
    lo[nt] = ((vox>>3)*10 + (vox&7))*80 + q*16;
  }
  f32x4 acc[MROW][2];
  #pragma unroll
  for (int mr=0;mr<MROW;mr++)
    #pragma unroll
    for (int nt=0;nt<2;nt++){ acc[mr][nt].x=0.f; acc[mr][nt].y=0.f; acc[mr][nt].z=0.f; acc[mr][nt].w=0.f; }

  const char* ldsb = reinterpret_cast<const char*>(xh);
  const char* wac  = reinterpret_cast<const char*>(wA);

  #pragma unroll 1
  for (int h=0; h<2; h++){
    if (h) __syncthreads();           // all waves done reading phase 0
    for (int it = tid; it < 2400; it += 256){
      int cg = it / 300; int pos = it - cg*300;
      int dz = pos/100; int r = pos - dz*100; int dy = r/10; int dxx = r - dy*10;
      int gz = z + dz - 1, gy = by + dy - 1, gx = bx + dxx - 1;
      bool ok = (gz>=0 && gz<DD && gy>=0 && gy<HH && gx>=0 && gx<WW);
      uint2 pk; pk.x = 0u; pk.y = 0u;
      if (ok){
        size_t gv = (size_t)((gz*HH+gy)*WW + gx);
        if (INPK){
          int cp0 = h*16 + cg*2;
          pk.x = xinp[(size_t)cp0*VV + gv];
          pk.y = xinp[(size_t)(cp0+1)*VV + gv];
        } else {
          int ci0 = h*32 + cg*4;
          float v0 = xin[(size_t)(ci0  )*VV + gv];
          float v1 = xin[(size_t)(ci0+1)*VV + gv];
          float v2 = xin[(size_t)(ci0+2)*VV + gv];
          float v3 = xin[(size_t)(ci0+3)*VV + gv];
          pk.x = packbf2(v0,v1); pk.y = packbf2(v2,v3);
        }
      }
      *reinterpret_cast<uint2*>(&xh[pos*40 + cg*4]) = pk;
    }
    __syncthreads();
    #pragma unroll 3
    for (int tap=0; tap<27; tap++){
      int dz = tap/9; int r9 = tap - dz*9; int dy = r9/3; int dxx = r9 - dy*3;
      int stepOff = (dz*100 + dy*10 + dxx)*80;
      int s = tap*2 + h;
      bf16x8 af[MROW];
      #pragma unroll
      for (int mr=0;mr<MROW;mr++)
        af[mr] = *reinterpret_cast<const bf16x8*>(wac + (size_t)((s*MG + mbase+mr)*64 + lane)*16);
      bf16x8 bf[2];
      #pragma unroll
      for (int nt=0;nt<2;nt++)
        bf[nt] = *reinterpret_cast<const bf16x8*>(ldsb + (lo[nt] + stepOff));
      #pragma unroll
      for (int mr=0;mr<MROW;mr++)
        #pragma unroll
        for (int nt=0;nt<2;nt++)
          acc[mr][nt] = __builtin_amdgcn_mfma_f32_16x16x32_bf16(af[mr], bf[nt], acc[mr][nt], 0, 0, 0);
    }
  }

  #pragma unroll
  for (int mr=0; mr<MROW; mr++){
    int cob = (mbase+mr)*16 + q*4;
    #pragma unroll
    for (int nt=0; nt<2; nt++){
      int vox = (np*2+nt)*16 + n;
      int vy = by + (vox>>3), vx = bx + (vox&7);
      size_t gv = (size_t)((z*HH + vy)*WW + vx);
      float r0 = acc[mr][nt].x, r1 = acc[mr][nt].y, r2 = acc[mr][nt].z, r3 = acc[mr][nt].w;
      if (OUTPK == 1){
        r0 += bias[cob+0]; r1 += bias[cob+1]; r2 += bias[cob+2]; r3 += bias[cob+3];
        r0 = 0.5f*r0*(1.f + erff(r0*0.70710678118654752f));
        r1 = 0.5f*r1*(1.f + erff(r1*0.70710678118654752f));
        r2 = 0.5f*r2*(1.f + erff(r2*0.70710678118654752f));
        r3 = 0.5f*r3*(1.f + erff(r3*0.70710678118654752f));
        uint* dst = (uint*)outp + (size_t)call*32*VV;
        dst[(size_t)(cob>>1)*VV + gv]     = packbf2(r0,r1);
        dst[(size_t)((cob>>1)+1)*VV + gv] = packbf2(r2,r3);
      } else {
        ushort* dst = (ushort*)outp + (size_t)call*96*VV;
        dst[(size_t)(cob+0)*VV + gv] = f2bf(tanhf(r0));
        dst[(size_t)(cob+1)*VV + gv] = f2bf(tanhf(r1));
        dst[(size_t)(cob+2)*VV + gv] = f2bf(tanhf(r2));
        dst[(size_t)(cob+3)*VV + gv] = f2bf(tanhf(r3));
      }
    }
  }
}

// ---- sampling geometry (replicates the reference's channel->axis swap) ---
struct Geom { int x0,x1,y0,y1,z0,z1; float wx,wy,wz; };
__device__ __forceinline__ Geom make_geom(float zb, float yb, float xb,
                                          float o0, float o1, float o2){
  float g0 = clampf(zb + o0*(1.f/16.f), -1.f, 1.f);
  float g1 = clampf(yb + o1*(1.f/64.f), -1.f, 1.f);
  float g2 = clampf(xb + o2*(1.f/64.f), -1.f, 1.f);
  float ix = (g0+1.f)*0.5f*63.f;
  float iy = (g1+1.f)*0.5f*63.f;
  float iz = (g2+1.f)*0.5f*15.f;
  float fx=floorf(ix), fy=floorf(iy), fz=floorf(iz);
  Geom g;
  g.wx = ix-fx; g.wy = iy-fy; g.wz = iz-fz;
  g.x0 = imin(imax((int)fx,0), WW-1); g.x1 = imin(g.x0+1, WW-1);
  g.y0 = imin(imax((int)fy,0), HH-1); g.y1 = imin(g.y0+1, HH-1);
  g.z0 = imin(imax((int)fz,0), DD-1); g.z1 = imin(g.z0+1, DD-1);
  return g;
}

// ---- sample + attention (online softmax) + MFMA out conv + BN + relu -----
// batched over both calls: grid 2048 blocks of 64 voxels x 4 heads
__global__ __launch_bounds__(256, 5) void sample_attn_kernel(
    const ushort* __restrict__ qbuf, const ushort* __restrict__ offbuf,
    const uint* __restrict__ vols, const uint* __restrict__ woA,
    const float* __restrict__ outb, const float* __restrict__ bng,
    const float* __restrict__ bnb, const float* __restrict__ bnm,
    const float* __restrict__ bnv, float* __restrict__ dout)
{
  __shared__ ushort fsb[64*72];   // fused attn output, bf16 [vox][ci], 144B rows
  int t = threadIdx.x;
  int lv = t & 63;
  int m = __builtin_amdgcn_readfirstlane(t >> 6);
  int bid = blockIdx.x;
  int xcd = bid & 7, islot = bid >> 3;
  int call = islot >> 7;
  int z = xcd*2 + ((islot >> 6) & 1);
  int y = islot & 63;
  int v0 = (z*HH + y)*WW;
  int v = v0 + lv;
  int x = lv;
  const ushort* qb = qbuf   + (size_t)call*CC*VV;
  const ushort* ob = offbuf + (size_t)call*96*VV;
  float zb = -1.f + (float)z*(2.f/15.f);
  float yb = -1.f + (float)y*(2.f/63.f);
  float xb = -1.f + (float)x*(2.f/63.f);
  float q[HDIM];
  #pragma unroll
  for (int c=0;c<HDIM;c++) q[c] = bf2f(qb[(size_t)(m*HDIM+c)*VV + v]);
  const uint* vol = vols + (size_t)m*VV*VOLU;
  float mrun = -1e30f, lrun = 0.f;
  float fused[HDIM];
  #pragma unroll
  for (int c=0;c<HDIM;c++) fused[c]=0.f;
  #pragma unroll 2
  for (int s=0;s<NSAMP;s++){
    float o0 = bf2f(ob[(size_t)(m*24 + s*3 + 0)*VV + v]);
    float o1 = bf2f(ob[(size_t)(m*24 + s*3 + 1)*VV + v]);
    float o2 = bf2f(ob[(size_t)(m*24 + s*3 + 2)*VV + v]);
    Geom g = make_geom(zb,yb,xb,o0,o1,o2);
    float lg = 0.f;
    float val[HDIM];
    #pragma unroll
    for (int c=0;c<HDIM;c++) val[c]=0.f;
    #pragma unroll
    for (int ky=0;ky<2;ky++)
    #pragma unroll
    for (int kx=0;kx<2;kx++){
      int cy = ky? g.y1:g.y0, cx = kx? g.x1:g.x0;
      float wyx = (ky? g.wy : 1.f-g.wy)*(kx? g.wx : 1.f-g.wx);
      size_t base = (size_t)(cy*WW + cx)*DD;
      #pragma unroll
      for (int kz=0;kz<2;kz++){
        int cz = kz? g.z1:g.z0;
        float cw = wyx * (kz? g.wz : 1.f-g.wz);
        const uint4* cp = reinterpret_cast<const uint4*>(vol + (base + cz)*VOLU);
#if USE_FP8
        uint4 kk = cp[0];             // 16 fp8 key
        uint4 vv = cp[1];             // 16 fp8 value
        lg += cw * dot16_fp8(kk, q);
        acc16_fp8(vv, cw, val);
#else
        uint4 k0 = cp[0], k1 = cp[1];
        uint4 vv0 = cp[2], vv1 = cp[3];
        lg += cw*(dot8(k0, q) + dot8(k1, q+8));
        acc8(vv0, cw, val);
        acc8(vv1, cw, val+8);
#endif
      }
    }
    float mnew = fmaxf(mrun, lg);
    float sc = expf(mrun - mnew);
    float e  = expf(lg - mnew);
    lrun = lrun*sc + e;
    #pragma unroll
    for (int c=0;c<HDIM;c++) fused[c] = fused[c]*sc + e*val[c];
    mrun = mnew;
  }
  float isum = 1.f/lrun;
  #pragma unroll
  for (int c2=0;c2<8;c2++)
    *reinterpret_cast<uint*>(&fsb[lv*72 + m*HDIM + 2*c2]) =
        packbf2(fused[2*c2]*isum, fused[2*c2+1]*isum);
  __syncthreads();

  // out 1x1 conv via MFMA: wave m computes co-tile m (16 co) x 64 vox
  int lane = t & 63;
  int qq = lane >> 4, n = lane & 15;
  f32x4 acc[4];
  #pragma unroll
  for (int nt=0;nt<4;nt++){ acc[nt].x=0.f; acc[nt].y=0.f; acc[nt].z=0.f; acc[nt].w=0.f; }
  const char* ldsb = reinterpret_cast<const char*>(fsb);
  const char* wac  = reinterpret_cast<const char*>(woA);
  #pragma unroll
  for (int ks=0; ks<2; ks++){
    bf16x8 af = *reinterpret_cast<const bf16x8*>(wac + (size_t)((ks*4 + m)*64 + lane)*16);
    #pragma unroll
    for (int nt=0; nt<4; nt++){
      bf16x8 bf = *reinterpret_cast<const bf16x8*>(ldsb + ((nt*16+n)*144 + qq*16 + ks*64));
      acc[nt] = __builtin_amdgcn_mfma_f32_16x16x32_bf16(af, bf, acc[nt], 0, 0, 0);
    }
  }
  int choff = 64 + call*64;
  #pragma unroll
  for (int nt=0; nt<4; nt++){
    int vv = v0 + nt*16 + n;
    #pragma unroll
    for (int rr=0; rr<4; rr++){
      int co = m*16 + qq*4 + rr;
      float inv = rsqrtf(bnv[co] + 1e-5f) * bng[co];
      float val = (acc[nt][rr] + outb[co] - bnm[co]) * inv + bnb[co];
      val = fmaxf(val, 0.f);
      dout[(size_t)(choff+co)*VV + vv] = val;
    }
  }
}

extern "C" void kernel_launch(void* const* d_in, const int* in_sizes, int n_in,
                              void* d_out, int out_size, void* d_ws, size_t ws_size,
                              hipStream_t stream){
  (void)in_sizes; (void)n_in; (void)out_size; (void)ws_size;
  const float* mid  = (const float*)d_in[0];
  const float* occ  = (const float*)d_in[1];
  const float* prev = (const float*)d_in[2];
  const float* off1w= (const float*)d_in[3];
  const float* off1b= (const float*)d_in[4];
  const float* off2w= (const float*)d_in[5];
  const float* kvw  = (const float*)d_in[6];
  const float* kvb  = (const float*)d_in[7];
  const float* qw   = (const float*)d_in[8];
  const float* qb   = (const float*)d_in[9];
  const float* outw = (const float*)d_in[10];
  const float* outb = (const float*)d_in[11];
  const float* bng  = (const float*)d_in[12];
  const float* bnb  = (const float*)d_in[13];
  const float* bnm  = (const float*)d_in[14];
  const float* bnv  = (const float*)d_in[15];
  float* out = (float*)d_out;

  uint*   vols  = (uint*)d_ws;                          // reserve 4*VV*16 uints
  ushort* qbuf  = (ushort*)(vols + (size_t)4*VV*16);    // 2*64*VV ushort
  uint*   o1pk  = (uint*)(qbuf + (size_t)2*CC*VV);      // 2*32*VV uint
  ushort* offb  = (ushort*)(o1pk + (size_t)2*32*VV);    // 2*96*VV ushort
  uint*   wA1   = (uint*)(offb + (size_t)2*96*VV);      // 55296
  uint*   wA2   = wA1 + 55296;                          // 82944
  uint*   wo    = wA2 + 82944;                          // 2048
  uint*   wkv   = wo  + 2048;                           // 4096
  uint*   wq    = wkv + 4096;                           // 2048

  repack_wmfma<<<(55296+255)/256, 256, 0, stream>>>(off1w, wA1, 4);
  repack_wmfma<<<(82944+255)/256, 256, 0, stream>>>(off2w, wA2, 6);
  repack_w1mfma<<<8, 256, 0, stream>>>(outw, wo, 4);
  repack_w1mfma<<<16, 256, 0, stream>>>(kvw, wkv, 8);
  repack_w1mfma<<<8, 256, 0, stream>>>(qw, wq, 4);
  conv1_mfma<128,0><<<1024, 256, 0, stream>>>(mid, mid, wkv, kvb, (void*)vols);
  hipMemcpyAsync(out, mid, (size_t)CC*VV*sizeof(float), hipMemcpyDeviceToDevice, stream);
  conv1_mfma<64,1><<<2048, 256, 0, stream>>>(occ, prev, wq, qb, (void*)qbuf);
  conv3_mfma<64,0,1><<<2048, 256, 0, stream>>>(occ, prev, (const uint*)nullptr, wA1, off1b, (void*)o1pk);
  conv3_mfma<96,1,0><<<2048, 256, 0, stream>>>((const float*)nullptr, (const float*)nullptr, o1pk, wA2, off1b, (void*)offb);
  sample_attn_kernel<<<2048, 256, 0, stream>>>(qbuf, offb, vols, wo,
      outb, bng, bnb, bnm, bnv, out);
}